// Round 8
// baseline (515.120 us; speedup 1.0000x reference)
//
#include <hip/hip_runtime.h>

// Problem constants
#define LSEQ 2048
#define DMODEL 512
#define DHD 64          // head dim of the (faithful) raw view
#define SLAB (LSEQ*DHD) // 131072 elements per contiguous head slab

typedef __attribute__((ext_vector_type(8))) short short8;
typedef __attribute__((ext_vector_type(4))) float f32x4;
typedef _Float16 half8 __attribute__((ext_vector_type(8)));
typedef _Float16 h4_t  __attribute__((ext_vector_type(4)));

__device__ __forceinline__ short f2bf(float x) {   // round-to-nearest-even bf16
    union { float f; unsigned u; } v; v.f = x;
    unsigned r = v.u + 0x7FFF + ((v.u >> 16) & 1);
    return (short)(r >> 16);
}
__device__ __forceinline__ float bf2f(short h) {
    union { float f; unsigned u; } v; v.u = ((unsigned)(unsigned short)h) << 16;
    return v.f;
}

// direct global->LDS async copy, 16 B per lane (dest = wave-uniform base + lane*16)
#define GLOAD_LDS16(g, l) __builtin_amdgcn_global_load_lds( \
    (const __attribute__((address_space(1))) void*)(g),     \
    (__attribute__((address_space(3))) void*)(l), 16, 0, 0)

#define VMCNT0()  asm volatile("s_waitcnt vmcnt(0)" ::: "memory")
#define VMCNT2()  asm volatile("s_waitcnt vmcnt(2)" ::: "memory")
#define BARRIER() do { __builtin_amdgcn_s_barrier(); __builtin_amdgcn_sched_barrier(0); } while (0)

// ---------------------------------------------------------------------------
// Projection GEMM: C[8192,512] = A[8192,512] @ W[512,512]^T + bias
// Internally split-f32 precision: a*w ~= ah*wh + ah*wl + al*wh (3 bf16 MFMAs).
// MODE 0: write f32 Cf.   MODE 3: write f16 C0 (round once at the end).
// ---------------------------------------------------------------------------
template<int MODE>
__global__ __launch_bounds__(256) void proj_gemm(
    const float* __restrict__ A, const float* __restrict__ W,
    const float* __restrict__ bias, float* __restrict__ Cf,
    short* __restrict__ C0)
{
    __shared__ __align__(16) short Ah[64][40], Al[64][40], Bh[64][40], Bl[64][40];

    const int tid  = threadIdx.x;
    const int lane = tid & 63, wv = tid >> 6;
    const int wm = wv >> 1, wn = wv & 1;
    const int fr = lane & 15, kg = lane >> 4;
    const int m0 = blockIdx.y * 64, n0 = blockIdx.x * 64;

    f32x4 acc[2][2];
    #pragma unroll
    for (int i = 0; i < 2; ++i)
        #pragma unroll
        for (int j = 0; j < 2; ++j) { f32x4 z = {0.f,0.f,0.f,0.f}; acc[i][j] = z; }

    const int srow = tid >> 2, sc8 = (tid & 3) << 3;

    for (int kt = 0; kt < 16; ++kt) {
        __syncthreads();
        {   // stage A/W tile, converting f32 -> hi/lo bf16
            const float* ap = A + (size_t)(m0 + srow) * DMODEL + kt*32 + sc8;
            float4 a0 = *(const float4*)ap;
            float4 a1 = *(const float4*)(ap + 4);
            float va[8] = {a0.x,a0.y,a0.z,a0.w,a1.x,a1.y,a1.z,a1.w};
            short8 h, l;
            #pragma unroll
            for (int j = 0; j < 8; ++j) { short hh = f2bf(va[j]); h[j] = hh; l[j] = f2bf(va[j] - bf2f(hh)); }
            *(short8*)&Ah[srow][sc8] = h; *(short8*)&Al[srow][sc8] = l;

            const float* wp = W + (size_t)(n0 + srow) * DMODEL + kt*32 + sc8;
            float4 b0 = *(const float4*)wp;
            float4 b1 = *(const float4*)(wp + 4);
            float vb[8] = {b0.x,b0.y,b0.z,b0.w,b1.x,b1.y,b1.z,b1.w};
            #pragma unroll
            for (int j = 0; j < 8; ++j) { short hh = f2bf(vb[j]); h[j] = hh; l[j] = f2bf(vb[j] - bf2f(hh)); }
            *(short8*)&Bh[srow][sc8] = h; *(short8*)&Bl[srow][sc8] = l;
        }
        __syncthreads();

        short8 ah[2], al[2], bh[2], bl[2];
        #pragma unroll
        for (int mf = 0; mf < 2; ++mf) {
            ah[mf] = *(short8*)&Ah[wm*32 + mf*16 + fr][kg*8];
            al[mf] = *(short8*)&Al[wm*32 + mf*16 + fr][kg*8];
        }
        #pragma unroll
        for (int nf = 0; nf < 2; ++nf) {
            bh[nf] = *(short8*)&Bh[wn*32 + nf*16 + fr][kg*8];
            bl[nf] = *(short8*)&Bl[wn*32 + nf*16 + fr][kg*8];
        }
        #pragma unroll
        for (int mf = 0; mf < 2; ++mf)
            #pragma unroll
            for (int nf = 0; nf < 2; ++nf) {
                acc[mf][nf] = __builtin_amdgcn_mfma_f32_16x16x32_bf16(ah[mf], bh[nf], acc[mf][nf], 0,0,0);
                acc[mf][nf] = __builtin_amdgcn_mfma_f32_16x16x32_bf16(ah[mf], bl[nf], acc[mf][nf], 0,0,0);
                acc[mf][nf] = __builtin_amdgcn_mfma_f32_16x16x32_bf16(al[mf], bh[nf], acc[mf][nf], 0,0,0);
            }
    }

    // epilogue: C/D layout col=lane&15, row=(lane>>4)*4+reg
    #pragma unroll
    for (int mf = 0; mf < 2; ++mf)
        #pragma unroll
        for (int nf = 0; nf < 2; ++nf) {
            const int col = n0 + wn*32 + nf*16 + fr;
            const float bv = bias[col];
            #pragma unroll
            for (int r = 0; r < 4; ++r) {
                const int row = m0 + wm*32 + mf*16 + kg*4 + r;
                const float o = acc[mf][nf][r] + bv;
                const size_t idx = (size_t)row * DMODEL + col;
                if (MODE == 0) Cf[idx] = o;
                else           ((_Float16*)C0)[idx] = (_Float16)o;
            }
        }
}

// ---------------------------------------------------------------------------
// V transpose: vt[head][d][l] = vf[head][l][d]  (f16, per-head [2048][64]->[64][2048])
// ---------------------------------------------------------------------------
__global__ __launch_bounds__(256) void vtrans_kernel(
    const short* __restrict__ vh, short* __restrict__ vt)
{
    __shared__ short T[64][72];
    const int tid = threadIdx.x;
    const int s  = blockIdx.y;          // head 0..31
    const int t0 = blockIdx.x * 64;     // row tile
    const size_t slab = (size_t)s * SLAB;

    {   // read 64x64 (coalesced 32 B / thread)
        const int r = tid >> 2, c0 = (tid & 3) << 4;
        const short* src = vh + slab + (size_t)(t0 + r) * DHD + c0;
        short8 a = *(const short8*)src;
        short8 b = *(const short8*)(src + 8);
        *(short8*)&T[r][c0]     = a;
        *(short8*)&T[r][c0 + 8] = b;
    }
    __syncthreads();
    {   // write transposed (32 B / thread)
        const int d = tid >> 2, r0 = (tid & 3) << 4;
        short8 o0, o1;
        #pragma unroll
        for (int j = 0; j < 8; ++j) { o0[j] = T[r0 + j][d]; o1[j] = T[r0 + 8 + j][d]; }
        short* dst = vt + slab + (size_t)d * LSEQ + t0 + r0;
        *(short8*)dst       = o0;
        *(short8*)(dst + 8) = o1;
    }
}

// ---------------------------------------------------------------------------
// Attention, one WG (512 thr / 8 waves) per (bh, 16-row q-tile). Single pass.
// SWAPPED QK^T: mfma(K, Q) -> lane holds P[k=i*128+wv*16+kg*4+{0..3}][q=fr].
//   Phase 1: K staged via swizzled-source global_load_lds, TRIPLE-buffered,
//            counted vmcnt(2); 2 raw barriers/iter.
//   Softmax: scalar per-lane m/li (all 4 comps share q=fr), 2 shfl_xor + LDS.
//   Phase 2: ZERO barriers / LDS / shuffles: float4 attn store straight from
//            regs; PV via legacy mfma_f32_16x16x16f16 (lane's own quad = B-frag),
//            V^T A-frags 8B contiguous from global vt (L2-resident).
//   Epilogue: 8-way k-slice reduce via padded LDS (aliases K buffer).
// ---------------------------------------------------------------------------
__global__ __launch_bounds__(512, 4) void attn_kernel(
    const _Float16* __restrict__ qf, const _Float16* __restrict__ kf,
    const _Float16* __restrict__ vt,
    float* __restrict__ attn, float* __restrict__ ctx)
{
    __shared__ __align__(16) char KBuf[49152];   // 3 x 16 KB K tile (128 rows x 64 f16)
    __shared__ float redA[8][16];
    __shared__ float mrow[16], lirow[16];

    const int tid  = threadIdx.x;
    const int lane = tid & 63, wv = tid >> 6;
    const int fr = lane & 15, kg = lane >> 4;

    // head-major remap: all 128 q-tiles of head bh land on XCD (bh&7)
    const int wg  = blockIdx.x;
    const int rem = wg & 1023;
    const int q0  = (rem >> 3) << 4;               // q-tile * 16
    const int bh  = ((wg >> 10) << 3) + (rem & 7); // 0..31
    const size_t slab = (size_t)bh * SLAB;

    // Q fragments (B-operand: lane fr holds row q0+fr), replicated across waves
    half8 qa[2];
    #pragma unroll
    for (int ks = 0; ks < 2; ++ks)
        qa[ks] = *(const half8*)(qf + slab + (size_t)(q0 + fr) * DHD + ks*32 + kg*8);

    const int srow = lane >> 3;          // staging: row within 8-row block
    const int scb  = (lane & 7) ^ srow;  // pre-swizzled global 16B col-block

    f32x4 s[16];   // logit quads: k = i*128 + wv*16 + kg*4 + r,  q = q0 + fr

    // ---- Phase 1: QK^T (swapped), triple-buffered K staging ----
    #define STAGE_K(TI, CUR) { \
        _Pragma("unroll") \
        for (int j = 0; j < 2; ++j) { \
            const int b = wv*2 + j; \
            GLOAD_LDS16(kf + slab + (size_t)((TI)*128 + b*8 + srow)*DHD + scb*8, \
                        KBuf + (CUR)*16384 + b*1024); \
        } }

    STAGE_K(0, 0);
    STAGE_K(1, 1);
    VMCNT0();
    BARRIER();

    const int klo = (wv << 4) + fr;          // tile-local K row 0..127
    const int sw  = fr & 7;                  // klo & 7
    #pragma unroll
    for (int i = 0; i < 16; ++i) {
        if (i + 2 < 16) STAGE_K(i + 2, (i + 2) % 3);

        const char* rp = KBuf + (i % 3)*16384 + (klo << 7);
        half8 kb0 = *(const half8*)(rp + ((kg ^ sw) << 4));
        half8 kb1 = *(const half8*)(rp + (((4 + kg) ^ sw) << 4));

        f32x4 a = {0.f,0.f,0.f,0.f};
        a = __builtin_amdgcn_mfma_f32_16x16x32_f16(kb0, qa[0], a, 0,0,0);  // SWAPPED
        a = __builtin_amdgcn_mfma_f32_16x16x32_f16(kb1, qa[1], a, 0,0,0);
        s[i] = a;

        if (i < 14)      VMCNT2();   // tile i+1's 2 loads retired
        else if (i == 14) VMCNT0();  // tail: drain tile 15
        if (i < 15) BARRIER();
    }
    #undef STAGE_K

    // ---- softmax: all 4 quad comps share q = fr -> scalar m / li ----
    float m;
    {
        f32x4 mx = s[0];
        #pragma unroll
        for (int i = 1; i < 16; ++i) {
            mx.x = fmaxf(mx.x, s[i].x); mx.y = fmaxf(mx.y, s[i].y);
            mx.z = fmaxf(mx.z, s[i].z); mx.w = fmaxf(mx.w, s[i].w);
        }
        m = fmaxf(fmaxf(mx.x, mx.y), fmaxf(mx.z, mx.w));
        m = fmaxf(m, __shfl_xor(m, 16));
        m = fmaxf(m, __shfl_xor(m, 32));
    }
    if (lane < 16) redA[wv][lane] = m;
    __syncthreads();
    if (tid < 16) {
        float mm = redA[0][tid];
        #pragma unroll
        for (int w = 1; w < 8; ++w) mm = fmaxf(mm, redA[w][tid]);
        mrow[tid] = mm;
    }
    __syncthreads();
    m = mrow[fr];

    const float C = 8.0f * 1.44269504089f;   // SCALE=8 folded into log2e
    float sum = 0.f;
    #pragma unroll
    for (int i = 0; i < 16; ++i) {
        f32x4 p;
        p.x = exp2f((s[i].x - m) * C);
        p.y = exp2f((s[i].y - m) * C);
        p.z = exp2f((s[i].z - m) * C);
        p.w = exp2f((s[i].w - m) * C);
        s[i] = p;
        sum += (p.x + p.y) + (p.z + p.w);
    }
    sum += __shfl_xor(sum, 16);
    sum += __shfl_xor(sum, 32);
    if (lane < 16) redA[wv][lane] = sum;
    __syncthreads();
    if (tid < 16) {
        float l = 0.f;
        #pragma unroll
        for (int w = 0; w < 8; ++w) l += redA[w][tid];
        lirow[tid] = 1.0f / l;
    }
    __syncthreads();
    const float li = lirow[fr];

    // ---- Phase 2: barrier-free attn store + PV (16x16x16 f16 MFMAs) ----
    f32x4 acc[4];
    #pragma unroll
    for (int db = 0; db < 4; ++db) { f32x4 z = {0.f,0.f,0.f,0.f}; acc[db] = z; }

    float* arow = attn + ((size_t)bh * LSEQ + q0 + fr) * LSEQ + (wv << 4) + (kg << 2);
    const _Float16* vbase = vt + slab + (size_t)fr * LSEQ + (wv << 4) + (kg << 2);

    #pragma unroll
    for (int t = 0; t < 16; ++t) {
        f32x4 p = s[t];
        p.x *= li; p.y *= li; p.z *= li; p.w *= li;
        float4 o = { p.x, p.y, p.z, p.w };
        *(float4*)(arow + (size_t)t * 128) = o;

        h4_t pk = { (_Float16)p.x, (_Float16)p.y, (_Float16)p.z, (_Float16)p.w };

        #pragma unroll
        for (int db = 0; db < 4; ++db) {
            h4_t va = *(const h4_t*)(vbase + (size_t)db * 16 * LSEQ + t * 128);
            acc[db] = __builtin_amdgcn_mfma_f32_16x16x16f16(va, pk, acc[db], 0,0,0);
        }
    }

    // ---- epilogue: 8-way k-slice reduce (aliases K buffer; stride 68 pads banks) ----
    {
        float* pt = (float*)KBuf;            // [8][16][68]
        #pragma unroll
        for (int db = 0; db < 4; ++db) {
            float4 o = { acc[db].x, acc[db].y, acc[db].z, acc[db].w };
            *(float4*)(pt + wv*1088 + fr*68 + db*16 + (kg << 2)) = o;
        }
    }
    __syncthreads();
    {
        float* pt = (float*)KBuf;
        const int e = tid << 1;              // 512 thr x 2 floats = 16x64
        const int q = e >> 6, d = e & 63;
        float2 r2 = {0.f, 0.f};
        #pragma unroll
        for (int w = 0; w < 8; ++w) {
            float2 t2 = *(float2*)(pt + w*1088 + q*68 + d);
            r2.x += t2.x; r2.y += t2.y;
        }
        *(float2*)(ctx + slab + (size_t)(q0 + q) * DHD + d) = r2;
    }
}

// ---------------------------------------------------------------------------
// Residual + LayerNorm: out = LN(resid + x) * gamma + beta, one row per block
// ---------------------------------------------------------------------------
__global__ __launch_bounds__(128) void ln_kernel(
    const float* __restrict__ resid, const float* __restrict__ x,
    const float* __restrict__ gamma, const float* __restrict__ beta,
    float* __restrict__ out)
{
    const int row = blockIdx.x;
    const int tid = threadIdx.x;
    const size_t base = (size_t)row * DMODEL + tid*4;

    float4 v = *(const float4*)(x + base);
    float4 rq = *(const float4*)(resid + base);
    v.x += rq.x; v.y += rq.y; v.z += rq.z; v.w += rq.w;

    float s  = v.x + v.y + v.z + v.w;
    float ss = v.x*v.x + v.y*v.y + v.z*v.z + v.w*v.w;
    #pragma unroll
    for (int d = 1; d < 64; d <<= 1) { s += __shfl_xor(s, d); ss += __shfl_xor(ss, d); }

    __shared__ float red[2][2];
    const int wv = tid >> 6;
    if ((tid & 63) == 0) { red[wv][0] = s; red[wv][1] = ss; }
    __syncthreads();
    s  = red[0][0] + red[1][0];
    ss = red[0][1] + red[1][1];

    const float mu  = s * (1.0f/512.0f);
    const float var = ss * (1.0f/512.0f) - mu*mu;
    const float rs  = rsqrtf(var + 1e-5f);

    float4 g = *(const float4*)(gamma + tid*4);
    float4 b = *(const float4*)(beta + tid*4);
    float4 o;
    o.x = (v.x - mu) * rs * g.x + b.x;
    o.y = (v.y - mu) * rs * g.y + b.y;
    o.z = (v.z - mu) * rs * g.z + b.z;
    o.w = (v.w - mu) * rs * g.w + b.w;
    *(float4*)(out + base) = o;
}

// ---------------------------------------------------------------------------
extern "C" void kernel_launch(void* const* d_in, const int* in_sizes, int n_in,
                              void* d_out, int out_size, void* d_ws, size_t ws_size,
                              hipStream_t stream)
{
    const float* query = (const float*)d_in[0];
    const float* key   = (const float*)d_in[1];
    const float* value = (const float*)d_in[2];
    const float* Wq = (const float*)d_in[3];
    const float* bq = (const float*)d_in[4];
    const float* Wk = (const float*)d_in[5];
    const float* bk = (const float*)d_in[6];
    const float* Wv = (const float*)d_in[7];
    const float* bv = (const float*)d_in[8];
    const float* Wo = (const float*)d_in[9];
    const float* bo = (const float*)d_in[10];
    const float* gamma = (const float*)d_in[11];
    const float* beta  = (const float*)d_in[12];

    float* out  = (float*)d_out;            // [B,L,D] = 4,194,304 f32
    float* attn = out + 4194304;            // [32,2048,2048] f32

    const size_t NTOK = (size_t)8192 * 512; // 4,194,304 elements
    short* qv = (short*)d_ws;               // f16 projected tensors
    short* kv = qv + NTOK;
    short* vf = kv + NTOK;
    short* vt = vf + NTOK;                  // V^T per head [64][2048] f16
    // obuf aliases qv/kv (dead after attn_kernel); ws requirement = 32 MB
    float* obuf = (float*)d_ws;

    dim3 pgrid(8, 128), pblk(256);
    proj_gemm<3><<<pgrid, pblk, 0, stream>>>(query, Wq, bq, nullptr, qv);
    proj_gemm<3><<<pgrid, pblk, 0, stream>>>(key,   Wk, bk, nullptr, kv);
    proj_gemm<3><<<pgrid, pblk, 0, stream>>>(value, Wv, bv, nullptr, vf);

    vtrans_kernel<<<dim3(32, 32), 256, 0, stream>>>(vf, vt);

    attn_kernel<<<4096, 512, 0, stream>>>((const _Float16*)qv, (const _Float16*)kv,
                                          (const _Float16*)vt, attn, out /*ctx*/);

    proj_gemm<0><<<pgrid, pblk, 0, stream>>>(out /*ctx*/, Wo, bo, obuf, nullptr);
    ln_kernel<<<8192, 128, 0, stream>>>(query, obuf, gamma, beta, out);
}

// Round 9
// 348.642 us; speedup vs baseline: 1.4775x; 1.4775x over previous
//
#include <hip/hip_runtime.h>

// Problem constants
#define LSEQ 2048
#define DMODEL 512
#define DHD 64          // head dim of the (faithful) raw view
#define SLAB (LSEQ*DHD) // 131072 elements per contiguous head slab

typedef __attribute__((ext_vector_type(8))) short short8;
typedef __attribute__((ext_vector_type(4))) float f32x4;
typedef _Float16 half8 __attribute__((ext_vector_type(8)));
typedef _Float16 h4_t  __attribute__((ext_vector_type(4)));

__device__ __forceinline__ short f2bf(float x) {   // round-to-nearest-even bf16
    union { float f; unsigned u; } v; v.f = x;
    unsigned r = v.u + 0x7FFF + ((v.u >> 16) & 1);
    return (short)(r >> 16);
}
__device__ __forceinline__ float bf2f(short h) {
    union { float f; unsigned u; } v; v.u = ((unsigned)(unsigned short)h) << 16;
    return v.f;
}

// direct global->LDS async copy, 16 B per lane (dest = wave-uniform base + lane*16)
#define GLOAD_LDS16(g, l) __builtin_amdgcn_global_load_lds( \
    (const __attribute__((address_space(1))) void*)(g),     \
    (__attribute__((address_space(3))) void*)(l), 16, 0, 0)

#define VMCNT0()  asm volatile("s_waitcnt vmcnt(0)" ::: "memory")
#define VMCNT2()  asm volatile("s_waitcnt vmcnt(2)" ::: "memory")
#define LGKM0()   asm volatile("s_waitcnt lgkmcnt(0)" ::: "memory")
#define BARRIER() do { __builtin_amdgcn_s_barrier(); __builtin_amdgcn_sched_barrier(0); } while (0)

// ---------------------------------------------------------------------------
// Projection GEMM: C[8192,512] = A[8192,512] @ W[512,512]^T + bias
// Internally split-f32 precision: a*w ~= ah*wh + ah*wl + al*wh (3 bf16 MFMAs).
// MODE 0: write f32 Cf.   MODE 3: write f16 C0 (round once at the end).
// ---------------------------------------------------------------------------
template<int MODE>
__global__ __launch_bounds__(256) void proj_gemm(
    const float* __restrict__ A, const float* __restrict__ W,
    const float* __restrict__ bias, float* __restrict__ Cf,
    short* __restrict__ C0)
{
    __shared__ __align__(16) short Ah[64][40], Al[64][40], Bh[64][40], Bl[64][40];

    const int tid  = threadIdx.x;
    const int lane = tid & 63, wv = tid >> 6;
    const int wm = wv >> 1, wn = wv & 1;
    const int fr = lane & 15, kg = lane >> 4;
    const int m0 = blockIdx.y * 64, n0 = blockIdx.x * 64;

    f32x4 acc[2][2];
    #pragma unroll
    for (int i = 0; i < 2; ++i)
        #pragma unroll
        for (int j = 0; j < 2; ++j) { f32x4 z = {0.f,0.f,0.f,0.f}; acc[i][j] = z; }

    const int srow = tid >> 2, sc8 = (tid & 3) << 3;

    for (int kt = 0; kt < 16; ++kt) {
        __syncthreads();
        {   // stage A/W tile, converting f32 -> hi/lo bf16
            const float* ap = A + (size_t)(m0 + srow) * DMODEL + kt*32 + sc8;
            float4 a0 = *(const float4*)ap;
            float4 a1 = *(const float4*)(ap + 4);
            float va[8] = {a0.x,a0.y,a0.z,a0.w,a1.x,a1.y,a1.z,a1.w};
            short8 h, l;
            #pragma unroll
            for (int j = 0; j < 8; ++j) { short hh = f2bf(va[j]); h[j] = hh; l[j] = f2bf(va[j] - bf2f(hh)); }
            *(short8*)&Ah[srow][sc8] = h; *(short8*)&Al[srow][sc8] = l;

            const float* wp = W + (size_t)(n0 + srow) * DMODEL + kt*32 + sc8;
            float4 b0 = *(const float4*)wp;
            float4 b1 = *(const float4*)(wp + 4);
            float vb[8] = {b0.x,b0.y,b0.z,b0.w,b1.x,b1.y,b1.z,b1.w};
            #pragma unroll
            for (int j = 0; j < 8; ++j) { short hh = f2bf(vb[j]); h[j] = hh; l[j] = f2bf(vb[j] - bf2f(hh)); }
            *(short8*)&Bh[srow][sc8] = h; *(short8*)&Bl[srow][sc8] = l;
        }
        __syncthreads();

        short8 ah[2], al[2], bh[2], bl[2];
        #pragma unroll
        for (int mf = 0; mf < 2; ++mf) {
            ah[mf] = *(short8*)&Ah[wm*32 + mf*16 + fr][kg*8];
            al[mf] = *(short8*)&Al[wm*32 + mf*16 + fr][kg*8];
        }
        #pragma unroll
        for (int nf = 0; nf < 2; ++nf) {
            bh[nf] = *(short8*)&Bh[wn*32 + nf*16 + fr][kg*8];
            bl[nf] = *(short8*)&Bl[wn*32 + nf*16 + fr][kg*8];
        }
        #pragma unroll
        for (int mf = 0; mf < 2; ++mf)
            #pragma unroll
            for (int nf = 0; nf < 2; ++nf) {
                acc[mf][nf] = __builtin_amdgcn_mfma_f32_16x16x32_bf16(ah[mf], bh[nf], acc[mf][nf], 0,0,0);
                acc[mf][nf] = __builtin_amdgcn_mfma_f32_16x16x32_bf16(ah[mf], bl[nf], acc[mf][nf], 0,0,0);
                acc[mf][nf] = __builtin_amdgcn_mfma_f32_16x16x32_bf16(al[mf], bh[nf], acc[mf][nf], 0,0,0);
            }
    }

    // epilogue: C/D layout col=lane&15, row=(lane>>4)*4+reg
    #pragma unroll
    for (int mf = 0; mf < 2; ++mf)
        #pragma unroll
        for (int nf = 0; nf < 2; ++nf) {
            const int col = n0 + wn*32 + nf*16 + fr;
            const float bv = bias[col];
            #pragma unroll
            for (int r = 0; r < 4; ++r) {
                const int row = m0 + wm*32 + mf*16 + kg*4 + r;
                const float o = acc[mf][nf][r] + bv;
                const size_t idx = (size_t)row * DMODEL + col;
                if (MODE == 0) Cf[idx] = o;
                else           ((_Float16*)C0)[idx] = (_Float16)o;
            }
        }
}

// ---------------------------------------------------------------------------
// V transpose -> FRAGMENT-MAJOR layout: vtf[head][kb][d][ks] with k = kb*16+ks.
// PV A-fragment for (tile, d-block) is then one fully-contiguous 512 B wave
// load (lane offset fr*16 + kg*4 within a 256-half block).
// ---------------------------------------------------------------------------
__global__ __launch_bounds__(256) void vtransf_kernel(
    const short* __restrict__ vh, short* __restrict__ vtf)
{
    __shared__ short T[64][72];
    const int tid = threadIdx.x;
    const int s  = blockIdx.y;          // head 0..31
    const int t0 = blockIdx.x * 64;     // l-tile (4 kb blocks)
    const size_t slab = (size_t)s * SLAB;

    {   // read 64 l-rows x 64 d (coalesced 32 B / thread)
        const int r = tid >> 2, c0 = (tid & 3) << 4;
        const short* src = vh + slab + (size_t)(t0 + r) * DHD + c0;
        short8 a = *(const short8*)src;
        short8 b = *(const short8*)(src + 8);
        *(short8*)&T[r][c0]     = a;
        *(short8*)&T[r][c0 + 8] = b;
    }
    __syncthreads();
    {   // write vtf[(kb*64 + d)*16 + ks] = T[kbl*16 + ks][d]  (32 B / thread)
        const int kbl = tid >> 6, d = tid & 63;
        short8 o0, o1;
        #pragma unroll
        for (int j = 0; j < 8; ++j) { o0[j] = T[kbl*16 + j][d]; o1[j] = T[kbl*16 + 8 + j][d]; }
        short* dst = vtf + slab + ((size_t)((t0 >> 4) + kbl) * 64 + d) * 16;
        *(short8*)dst       = o0;
        *(short8*)(dst + 8) = o1;
    }
}

// ---------------------------------------------------------------------------
// Attention, one WG (512 thr / 8 waves) per (bh, 16-row q-tile). Single pass.
// SWAPPED QK^T: mfma(K, Q) -> lane holds P[k=i*128+wv*16+kg*4+{0..3}][q=fr]
// (layout verified by round-8 absmax).
//   Phase 1: K staged via swizzled-source global_load_lds, triple-buffered,
//            counted vmcnt(2); raw barriers.
//   Softmax: scalar per-lane m/li, 2 shfl_xor + small LDS combine.
//   Phase 2: PV from own regs + fragment-major V (512 B coalesced wave loads,
//            zero LDS reads); attn store via f16 PB tile (dbuf, 1 barrier/t)
//            -> 512 B/row full-line coalesced f32 stores.
//   Epilogue: 8-way k-slice reduce via padded LDS (aliases K buffer).
// ---------------------------------------------------------------------------
__global__ __launch_bounds__(512, 4) void attn_kernel(
    const _Float16* __restrict__ qf, const _Float16* __restrict__ kf,
    const _Float16* __restrict__ vtf,
    float* __restrict__ attn, float* __restrict__ ctx)
{
    __shared__ __align__(16) char KBuf[49152];        // 3 x 16 KB K tile
    __shared__ __align__(16) _Float16 PB[2][16][136]; // 8,704 B P tile (store path)
    __shared__ float redA[8][16];
    __shared__ float mrow[16], lirow[16];

    const int tid  = threadIdx.x;
    const int lane = tid & 63, wv = tid >> 6;
    const int fr = lane & 15, kg = lane >> 4;

    // head-major remap: all 128 q-tiles of head bh land on XCD (bh&7)
    const int wg  = blockIdx.x;
    const int rem = wg & 1023;
    const int q0  = (rem >> 3) << 4;               // q-tile * 16
    const int bh  = ((wg >> 10) << 3) + (rem & 7); // 0..31
    const size_t slab = (size_t)bh * SLAB;

    // Q fragments (B-operand: lane fr holds row q0+fr), replicated across waves
    half8 qa[2];
    #pragma unroll
    for (int ks = 0; ks < 2; ++ks)
        qa[ks] = *(const half8*)(qf + slab + (size_t)(q0 + fr) * DHD + ks*32 + kg*8);

    const int srow = lane >> 3;          // staging: row within 8-row block
    const int scb  = (lane & 7) ^ srow;  // pre-swizzled global 16B col-block

    f32x4 s[16];   // logit quads: k = i*128 + wv*16 + kg*4 + r,  q = q0 + fr

    // ---- Phase 1: QK^T (swapped), triple-buffered K staging ----
    #define STAGE_K(TI, CUR) { \
        _Pragma("unroll") \
        for (int j = 0; j < 2; ++j) { \
            const int b = wv*2 + j; \
            GLOAD_LDS16(kf + slab + (size_t)((TI)*128 + b*8 + srow)*DHD + scb*8, \
                        KBuf + (CUR)*16384 + b*1024); \
        } }

    STAGE_K(0, 0);
    STAGE_K(1, 1);
    VMCNT0();
    BARRIER();

    const int klo = (wv << 4) + fr;          // tile-local K row 0..127
    const int sw  = fr & 7;                  // klo & 7
    #pragma unroll
    for (int i = 0; i < 16; ++i) {
        if (i + 2 < 16) STAGE_K(i + 2, (i + 2) % 3);

        const char* rp = KBuf + (i % 3)*16384 + (klo << 7);
        half8 kb0 = *(const half8*)(rp + ((kg ^ sw) << 4));
        half8 kb1 = *(const half8*)(rp + (((4 + kg) ^ sw) << 4));

        f32x4 a = {0.f,0.f,0.f,0.f};
        a = __builtin_amdgcn_mfma_f32_16x16x32_f16(kb0, qa[0], a, 0,0,0);  // SWAPPED
        a = __builtin_amdgcn_mfma_f32_16x16x32_f16(kb1, qa[1], a, 0,0,0);
        s[i] = a;

        if (i < 14)      VMCNT2();   // tile i+1's 2 loads retired
        else if (i == 14) VMCNT0();  // tail: drain tile 15
        if (i < 15) BARRIER();
    }
    #undef STAGE_K

    // ---- softmax: all 4 quad comps share q = fr -> scalar m / li ----
    float m;
    {
        f32x4 mx = s[0];
        #pragma unroll
        for (int i = 1; i < 16; ++i) {
            mx.x = fmaxf(mx.x, s[i].x); mx.y = fmaxf(mx.y, s[i].y);
            mx.z = fmaxf(mx.z, s[i].z); mx.w = fmaxf(mx.w, s[i].w);
        }
        m = fmaxf(fmaxf(mx.x, mx.y), fmaxf(mx.z, mx.w));
        m = fmaxf(m, __shfl_xor(m, 16));
        m = fmaxf(m, __shfl_xor(m, 32));
    }
    if (lane < 16) redA[wv][lane] = m;
    __syncthreads();
    if (tid < 16) {
        float mm = redA[0][tid];
        #pragma unroll
        for (int w = 1; w < 8; ++w) mm = fmaxf(mm, redA[w][tid]);
        mrow[tid] = mm;
    }
    __syncthreads();
    m = mrow[fr];

    const float C = 8.0f * 1.44269504089f;   // SCALE=8 folded into log2e
    float sum = 0.f;
    #pragma unroll
    for (int i = 0; i < 16; ++i) {
        f32x4 p;
        p.x = exp2f((s[i].x - m) * C);
        p.y = exp2f((s[i].y - m) * C);
        p.z = exp2f((s[i].z - m) * C);
        p.w = exp2f((s[i].w - m) * C);
        s[i] = p;
        sum += (p.x + p.y) + (p.z + p.w);
    }
    sum += __shfl_xor(sum, 16);
    sum += __shfl_xor(sum, 32);
    if (lane < 16) redA[wv][lane] = sum;
    __syncthreads();
    if (tid < 16) {
        float l = 0.f;
        #pragma unroll
        for (int w = 0; w < 8; ++w) l += redA[w][tid];
        lirow[tid] = 1.0f / l;
    }
    __syncthreads();
    const float li = lirow[fr];

    // ---- Phase 2: PV (reg P + fragment-major V) + coalesced attn store ----
    f32x4 acc[4];
    #pragma unroll
    for (int db = 0; db < 4; ++db) { f32x4 z = {0.f,0.f,0.f,0.f}; acc[db] = z; }

    const _Float16* vfb = vtf + slab;        // fragment-major V
    const int sq = tid >> 5, sc = tid & 31;  // store mapping: row q, 4-col chunk
    float* abase = attn + ((size_t)bh * LSEQ + q0 + sq) * LSEQ + (sc << 2);

    int cur = 0;
    #pragma unroll
    for (int t = 0; t < 16; ++t) {
        // normalized P quad (k = t*128 + wv*16 + kg*4 + r, q = fr)
        f32x4 p = s[t];
        p.x *= li; p.y *= li; p.z *= li; p.w *= li;
        h4_t pw = { (_Float16)p.x, (_Float16)p.y, (_Float16)p.z, (_Float16)p.w };

        // PB write for the store path (8 B contiguous per lane)
        *(h4_t*)&PB[cur][fr][(wv << 4) + (kg << 2)] = pw;

        // PV: A-frag = 512 B contiguous wave load from vtf block kb = t*8+wv
        const _Float16* vb = vfb + ((size_t)(t*8 + wv) << 10) + (fr << 4) + (kg << 2);
        #pragma unroll
        for (int db = 0; db < 4; ++db) {
            h4_t va = *(const h4_t*)(vb + db*256);
            acc[db] = __builtin_amdgcn_mfma_f32_16x16x16f16(va, pw, acc[db], 0,0,0);
        }

        LGKM0();                   // PB writes landed
        BARRIER();                 // whole P tile ready

        // coalesced store: 512 thr -> 16 rows x 512 B full lines
        h4_t pr = *(const h4_t*)&PB[cur][sq][sc << 2];
        float4 o = { (float)pr[0], (float)pr[1], (float)pr[2], (float)pr[3] };
        *(float4*)(abase + (size_t)t * 128) = o;

        cur ^= 1;
    }

    // ---- epilogue: 8-way k-slice reduce (aliases K buffer; stride 68 pads banks) ----
    __syncthreads();
    {
        float* pt = (float*)KBuf;            // [8][16][68]
        #pragma unroll
        for (int db = 0; db < 4; ++db) {
            float4 o = { acc[db].x, acc[db].y, acc[db].z, acc[db].w };
            *(float4*)(pt + wv*1088 + fr*68 + db*16 + (kg << 2)) = o;
        }
    }
    __syncthreads();
    {
        float* pt = (float*)KBuf;
        const int e = tid << 1;              // 512 thr x 2 floats = 16x64
        const int q = e >> 6, d = e & 63;
        float2 r2 = {0.f, 0.f};
        #pragma unroll
        for (int w = 0; w < 8; ++w) {
            float2 t2 = *(float2*)(pt + w*1088 + q*68 + d);
            r2.x += t2.x; r2.y += t2.y;
        }
        *(float2*)(ctx + slab + (size_t)(q0 + q) * DHD + d) = r2;
    }
}

// ---------------------------------------------------------------------------
// Residual + LayerNorm: out = LN(resid + x) * gamma + beta, one row per block
// ---------------------------------------------------------------------------
__global__ __launch_bounds__(128) void ln_kernel(
    const float* __restrict__ resid, const float* __restrict__ x,
    const float* __restrict__ gamma, const float* __restrict__ beta,
    float* __restrict__ out)
{
    const int row = blockIdx.x;
    const int tid = threadIdx.x;
    const size_t base = (size_t)row * DMODEL + tid*4;

    float4 v = *(const float4*)(x + base);
    float4 rq = *(const float4*)(resid + base);
    v.x += rq.x; v.y += rq.y; v.z += rq.z; v.w += rq.w;

    float s  = v.x + v.y + v.z + v.w;
    float ss = v.x*v.x + v.y*v.y + v.z*v.z + v.w*v.w;
    #pragma unroll
    for (int d = 1; d < 64; d <<= 1) { s += __shfl_xor(s, d); ss += __shfl_xor(ss, d); }

    __shared__ float red[2][2];
    const int wv = tid >> 6;
    if ((tid & 63) == 0) { red[wv][0] = s; red[wv][1] = ss; }
    __syncthreads();
    s  = red[0][0] + red[1][0];
    ss = red[0][1] + red[1][1];

    const float mu  = s * (1.0f/512.0f);
    const float var = ss * (1.0f/512.0f) - mu*mu;
    const float rs  = rsqrtf(var + 1e-5f);

    float4 g = *(const float4*)(gamma + tid*4);
    float4 b = *(const float4*)(beta + tid*4);
    float4 o;
    o.x = (v.x - mu) * rs * g.x + b.x;
    o.y = (v.y - mu) * rs * g.y + b.y;
    o.z = (v.z - mu) * rs * g.z + b.z;
    o.w = (v.w - mu) * rs * g.w + b.w;
    *(float4*)(out + base) = o;
}

// ---------------------------------------------------------------------------
extern "C" void kernel_launch(void* const* d_in, const int* in_sizes, int n_in,
                              void* d_out, int out_size, void* d_ws, size_t ws_size,
                              hipStream_t stream)
{
    const float* query = (const float*)d_in[0];
    const float* key   = (const float*)d_in[1];
    const float* value = (const float*)d_in[2];
    const float* Wq = (const float*)d_in[3];
    const float* bq = (const float*)d_in[4];
    const float* Wk = (const float*)d_in[5];
    const float* bk = (const float*)d_in[6];
    const float* Wv = (const float*)d_in[7];
    const float* bv = (const float*)d_in[8];
    const float* Wo = (const float*)d_in[9];
    const float* bo = (const float*)d_in[10];
    const float* gamma = (const float*)d_in[11];
    const float* beta  = (const float*)d_in[12];

    float* out  = (float*)d_out;            // [B,L,D] = 4,194,304 f32
    float* attn = out + 4194304;            // [32,2048,2048] f32

    const size_t NTOK = (size_t)8192 * 512; // 4,194,304 elements
    short* qv = (short*)d_ws;               // f16 projected tensors
    short* kv = qv + NTOK;
    short* vf = kv + NTOK;
    short* vtf = vf + NTOK;                 // fragment-major V^T per head
    // obuf aliases qv/kv (dead after attn_kernel); ws requirement = 32 MB
    float* obuf = (float*)d_ws;

    dim3 pgrid(8, 128), pblk(256);
    proj_gemm<3><<<pgrid, pblk, 0, stream>>>(query, Wq, bq, nullptr, qv);
    proj_gemm<3><<<pgrid, pblk, 0, stream>>>(key,   Wk, bk, nullptr, kv);
    proj_gemm<3><<<pgrid, pblk, 0, stream>>>(value, Wv, bv, nullptr, vf);

    vtransf_kernel<<<dim3(32, 32), 256, 0, stream>>>(vf, vtf);

    attn_kernel<<<4096, 512, 0, stream>>>((const _Float16*)qv, (const _Float16*)kv,
                                          (const _Float16*)vtf, attn, out /*ctx*/);

    proj_gemm<0><<<pgrid, pblk, 0, stream>>>(out /*ctx*/, Wo, bo, obuf, nullptr);
    ln_kernel<<<8192, 128, 0, stream>>>(query, obuf, gamma, beta, out);
}

// Round 11
// 297.416 us; speedup vs baseline: 1.7320x; 1.1722x over previous
//
#include <hip/hip_runtime.h>

// Problem constants
#define LSEQ 2048
#define DMODEL 512
#define DHD 64          // head dim of the (faithful) raw view
#define SLAB (LSEQ*DHD) // 131072 elements per contiguous head slab

typedef __attribute__((ext_vector_type(8))) short short8;
typedef __attribute__((ext_vector_type(4))) float f32x4;
typedef float f4raw __attribute__((ext_vector_type(4)));   // raw clang vector (NT-store legal)
typedef _Float16 half8 __attribute__((ext_vector_type(8)));
typedef _Float16 h4_t  __attribute__((ext_vector_type(4)));

__device__ __forceinline__ short f2bf(float x) {   // round-to-nearest-even bf16
    union { float f; unsigned u; } v; v.f = x;
    unsigned r = v.u + 0x7FFF + ((v.u >> 16) & 1);
    return (short)(r >> 16);
}
__device__ __forceinline__ float bf2f(short h) {
    union { float f; unsigned u; } v; v.u = ((unsigned)(unsigned short)h) << 16;
    return v.f;
}

// direct global->LDS async copy, 16 B per lane (dest = wave-uniform base + lane*16)
#define GLOAD_LDS16(g, l) __builtin_amdgcn_global_load_lds( \
    (const __attribute__((address_space(1))) void*)(g),     \
    (__attribute__((address_space(3))) void*)(l), 16, 0, 0)

#define VMCNT0()  asm volatile("s_waitcnt vmcnt(0)" ::: "memory")
#define LGKM0()   asm volatile("s_waitcnt lgkmcnt(0)" ::: "memory")
#define BARRIER() do { __builtin_amdgcn_s_barrier(); __builtin_amdgcn_sched_barrier(0); } while (0)

// ---------------------------------------------------------------------------
// Projection GEMM: C[8192,512] = A[8192,512] @ W[512,512]^T + bias
// Internally split-f32 precision: a*w ~= ah*wh + ah*wl + al*wh (3 bf16 MFMAs).
// MODE 0: write f32 Cf.   MODE 3: write f16 C0 (round once at the end).
// ---------------------------------------------------------------------------
template<int MODE>
__global__ __launch_bounds__(256) void proj_gemm(
    const float* __restrict__ A, const float* __restrict__ W,
    const float* __restrict__ bias, float* __restrict__ Cf,
    short* __restrict__ C0)
{
    __shared__ __align__(16) short Ah[64][40], Al[64][40], Bh[64][40], Bl[64][40];

    const int tid  = threadIdx.x;
    const int lane = tid & 63, wv = tid >> 6;
    const int wm = wv >> 1, wn = wv & 1;
    const int fr = lane & 15, kg = lane >> 4;
    const int m0 = blockIdx.y * 64, n0 = blockIdx.x * 64;

    f32x4 acc[2][2];
    #pragma unroll
    for (int i = 0; i < 2; ++i)
        #pragma unroll
        for (int j = 0; j < 2; ++j) { f32x4 z = {0.f,0.f,0.f,0.f}; acc[i][j] = z; }

    const int srow = tid >> 2, sc8 = (tid & 3) << 3;

    for (int kt = 0; kt < 16; ++kt) {
        __syncthreads();
        {   // stage A/W tile, converting f32 -> hi/lo bf16
            const float* ap = A + (size_t)(m0 + srow) * DMODEL + kt*32 + sc8;
            float4 a0 = *(const float4*)ap;
            float4 a1 = *(const float4*)(ap + 4);
            float va[8] = {a0.x,a0.y,a0.z,a0.w,a1.x,a1.y,a1.z,a1.w};
            short8 h, l;
            #pragma unroll
            for (int j = 0; j < 8; ++j) { short hh = f2bf(va[j]); h[j] = hh; l[j] = f2bf(va[j] - bf2f(hh)); }
            *(short8*)&Ah[srow][sc8] = h; *(short8*)&Al[srow][sc8] = l;

            const float* wp = W + (size_t)(n0 + srow) * DMODEL + kt*32 + sc8;
            float4 b0 = *(const float4*)wp;
            float4 b1 = *(const float4*)(wp + 4);
            float vb[8] = {b0.x,b0.y,b0.z,b0.w,b1.x,b1.y,b1.z,b1.w};
            #pragma unroll
            for (int j = 0; j < 8; ++j) { short hh = f2bf(vb[j]); h[j] = hh; l[j] = f2bf(vb[j] - bf2f(hh)); }
            *(short8*)&Bh[srow][sc8] = h; *(short8*)&Bl[srow][sc8] = l;
        }
        __syncthreads();

        short8 ah[2], al[2], bh[2], bl[2];
        #pragma unroll
        for (int mf = 0; mf < 2; ++mf) {
            ah[mf] = *(short8*)&Ah[wm*32 + mf*16 + fr][kg*8];
            al[mf] = *(short8*)&Al[wm*32 + mf*16 + fr][kg*8];
        }
        #pragma unroll
        for (int nf = 0; nf < 2; ++nf) {
            bh[nf] = *(short8*)&Bh[wn*32 + nf*16 + fr][kg*8];
            bl[nf] = *(short8*)&Bl[wn*32 + nf*16 + fr][kg*8];
        }
        #pragma unroll
        for (int mf = 0; mf < 2; ++mf)
            #pragma unroll
            for (int nf = 0; nf < 2; ++nf) {
                acc[mf][nf] = __builtin_amdgcn_mfma_f32_16x16x32_bf16(ah[mf], bh[nf], acc[mf][nf], 0,0,0);
                acc[mf][nf] = __builtin_amdgcn_mfma_f32_16x16x32_bf16(ah[mf], bl[nf], acc[mf][nf], 0,0,0);
                acc[mf][nf] = __builtin_amdgcn_mfma_f32_16x16x32_bf16(al[mf], bh[nf], acc[mf][nf], 0,0,0);
            }
    }

    // epilogue: C/D layout col=lane&15, row=(lane>>4)*4+reg
    #pragma unroll
    for (int mf = 0; mf < 2; ++mf)
        #pragma unroll
        for (int nf = 0; nf < 2; ++nf) {
            const int col = n0 + wn*32 + nf*16 + fr;
            const float bv = bias[col];
            #pragma unroll
            for (int r = 0; r < 4; ++r) {
                const int row = m0 + wm*32 + mf*16 + kg*4 + r;
                const float o = acc[mf][nf][r] + bv;
                const size_t idx = (size_t)row * DMODEL + col;
                if (MODE == 0) Cf[idx] = o;
                else           ((_Float16*)C0)[idx] = (_Float16)o;
            }
        }
}

// ---------------------------------------------------------------------------
// V transpose -> FRAGMENT-MAJOR layout: vtf[head][kb][d][ks] with k = kb*16+ks.
// PV A-fragment for (tile, d-block) is then one fully-contiguous 512 B wave
// load (lane offset fr*16 + kg*4 within a 256-half block).
// ---------------------------------------------------------------------------
__global__ __launch_bounds__(256) void vtransf_kernel(
    const short* __restrict__ vh, short* __restrict__ vtf)
{
    __shared__ short T[64][72];
    const int tid = threadIdx.x;
    const int s  = blockIdx.y;          // head 0..31
    const int t0 = blockIdx.x * 64;     // l-tile (4 kb blocks)
    const size_t slab = (size_t)s * SLAB;

    {   // read 64 l-rows x 64 d (coalesced 32 B / thread)
        const int r = tid >> 2, c0 = (tid & 3) << 4;
        const short* src = vh + slab + (size_t)(t0 + r) * DHD + c0;
        short8 a = *(const short8*)src;
        short8 b = *(const short8*)(src + 8);
        *(short8*)&T[r][c0]     = a;
        *(short8*)&T[r][c0 + 8] = b;
    }
    __syncthreads();
    {   // write vtf[(kb*64 + d)*16 + ks] = T[kbl*16 + ks][d]  (32 B / thread)
        const int kbl = tid >> 6, d = tid & 63;
        short8 o0, o1;
        #pragma unroll
        for (int j = 0; j < 8; ++j) { o0[j] = T[kbl*16 + j][d]; o1[j] = T[kbl*16 + 8 + j][d]; }
        short* dst = vtf + slab + ((size_t)((t0 >> 4) + kbl) * 64 + d) * 16;
        *(short8*)dst       = o0;
        *(short8*)(dst + 8) = o1;
    }
}

// ---------------------------------------------------------------------------
// Attention, one WG (512 thr / 8 waves) per (bh, 16-row q-tile). Single pass.
// SWAPPED QK^T: mfma(K, Q) -> lane holds P[k=i*128+wv*16+kg*4+{0..3}][q=fr].
//   Phase 1: K staged via swizzled-source global_load_lds, DOUBLE-buffered
//            (round-6-proven VMCNT0 + 1 barrier/iter schedule) -> LDS 42 KB
//            for 3 WGs/CU.
//   Softmax: scalar per-lane m/li, 2 shfl_xor + small LDS combine.
//   Phase 2: PV from own regs + fragment-major V (512 B coalesced wave loads);
//            attn stored NON-TEMPORAL (write-once stream; keeps K/V in L2)
//            via f16 PB tile -> full-line coalesced float4 stores.
//   Epilogue: 8-way k-slice reduce via LDS (aliases K buffer, exactly 32 KB).
// ---------------------------------------------------------------------------
__global__ __launch_bounds__(512, 4) void attn_kernel(
    const _Float16* __restrict__ qf, const _Float16* __restrict__ kf,
    const _Float16* __restrict__ vtf,
    float* __restrict__ attn, float* __restrict__ ctx)
{
    __shared__ __align__(16) char KBuf[32768];        // 2 x 16 KB K tile
    __shared__ __align__(16) _Float16 PB[2][16][136]; // 8,704 B P tile (store path)
    __shared__ float redA[8][16];
    __shared__ float mrow[16], lirow[16];

    const int tid  = threadIdx.x;
    const int lane = tid & 63, wv = tid >> 6;
    const int fr = lane & 15, kg = lane >> 4;

    // head-major remap: all 128 q-tiles of head bh land on XCD (bh&7)
    const int wg  = blockIdx.x;
    const int rem = wg & 1023;
    const int q0  = (rem >> 3) << 4;               // q-tile * 16
    const int bh  = ((wg >> 10) << 3) + (rem & 7); // 0..31
    const size_t slab = (size_t)bh * SLAB;

    // Q fragments (B-operand: lane fr holds row q0+fr), replicated across waves
    half8 qa[2];
    #pragma unroll
    for (int ks = 0; ks < 2; ++ks)
        qa[ks] = *(const half8*)(qf + slab + (size_t)(q0 + fr) * DHD + ks*32 + kg*8);

    const int srow = lane >> 3;          // staging: row within 8-row block
    const int scb  = (lane & 7) ^ srow;  // pre-swizzled global 16B col-block

    f32x4 s[16];   // logit quads: k = i*128 + wv*16 + kg*4 + r,  q = q0 + fr

    // ---- Phase 1: QK^T (swapped), double-buffered K staging ----
    #define STAGE_K(TI, CUR) { \
        _Pragma("unroll") \
        for (int j = 0; j < 2; ++j) { \
            const int b = wv*2 + j; \
            GLOAD_LDS16(kf + slab + (size_t)((TI)*128 + b*8 + srow)*DHD + scb*8, \
                        KBuf + (CUR)*16384 + b*1024); \
        } }

    STAGE_K(0, 0);
    VMCNT0();
    BARRIER();

    const int klo = (wv << 4) + fr;          // tile-local K row 0..127
    const int sw  = fr & 7;                  // klo & 7
    int cur = 0;
    #pragma unroll
    for (int i = 0; i < 16; ++i) {
        if (i < 15) STAGE_K(i + 1, cur ^ 1);  // issue next-tile loads first

        const char* rp = KBuf + cur*16384 + (klo << 7);
        half8 kb0 = *(const half8*)(rp + ((kg ^ sw) << 4));
        half8 kb1 = *(const half8*)(rp + (((4 + kg) ^ sw) << 4));

        f32x4 a = {0.f,0.f,0.f,0.f};
        a = __builtin_amdgcn_mfma_f32_16x16x32_f16(kb0, qa[0], a, 0,0,0);  // SWAPPED
        a = __builtin_amdgcn_mfma_f32_16x16x32_f16(kb1, qa[1], a, 0,0,0);
        s[i] = a;

        VMCNT0();                   // next tile landed
        BARRIER();                  // all waves done with cur + have next
        cur ^= 1;
    }
    #undef STAGE_K

    // ---- softmax: all 4 quad comps share q = fr -> scalar m / li ----
    float m;
    {
        f32x4 mx = s[0];
        #pragma unroll
        for (int i = 1; i < 16; ++i) {
            mx.x = fmaxf(mx.x, s[i].x); mx.y = fmaxf(mx.y, s[i].y);
            mx.z = fmaxf(mx.z, s[i].z); mx.w = fmaxf(mx.w, s[i].w);
        }
        m = fmaxf(fmaxf(mx.x, mx.y), fmaxf(mx.z, mx.w));
        m = fmaxf(m, __shfl_xor(m, 16));
        m = fmaxf(m, __shfl_xor(m, 32));
    }
    if (lane < 16) redA[wv][lane] = m;
    __syncthreads();
    if (tid < 16) {
        float mm = redA[0][tid];
        #pragma unroll
        for (int w = 1; w < 8; ++w) mm = fmaxf(mm, redA[w][tid]);
        mrow[tid] = mm;
    }
    __syncthreads();
    m = mrow[fr];

    const float C = 8.0f * 1.44269504089f;   // SCALE=8 folded into log2e
    float sum = 0.f;
    #pragma unroll
    for (int i = 0; i < 16; ++i) {
        f32x4 p;
        p.x = exp2f((s[i].x - m) * C);
        p.y = exp2f((s[i].y - m) * C);
        p.z = exp2f((s[i].z - m) * C);
        p.w = exp2f((s[i].w - m) * C);
        s[i] = p;
        sum += (p.x + p.y) + (p.z + p.w);
    }
    sum += __shfl_xor(sum, 16);
    sum += __shfl_xor(sum, 32);
    if (lane < 16) redA[wv][lane] = sum;
    __syncthreads();
    if (tid < 16) {
        float l = 0.f;
        #pragma unroll
        for (int w = 0; w < 8; ++w) l += redA[w][tid];
        lirow[tid] = 1.0f / l;
    }
    __syncthreads();
    const float li = lirow[fr];

    // ---- Phase 2: PV (reg P + fragment-major V) + coalesced NT attn store ----
    f32x4 acc[4];
    #pragma unroll
    for (int db = 0; db < 4; ++db) { f32x4 z = {0.f,0.f,0.f,0.f}; acc[db] = z; }

    const _Float16* vfb = vtf + slab;        // fragment-major V
    const int sq = tid >> 5, sc = tid & 31;  // store mapping: row q, 4-col chunk
    float* abase = attn + ((size_t)bh * LSEQ + q0 + sq) * LSEQ + (sc << 2);

    cur = 0;
    #pragma unroll
    for (int t = 0; t < 16; ++t) {
        // normalized P quad (k = t*128 + wv*16 + kg*4 + r, q = fr)
        f32x4 p = s[t];
        p.x *= li; p.y *= li; p.z *= li; p.w *= li;
        h4_t pw = { (_Float16)p.x, (_Float16)p.y, (_Float16)p.z, (_Float16)p.w };

        // PB write for the store path (8 B contiguous per lane)
        *(h4_t*)&PB[cur][fr][(wv << 4) + (kg << 2)] = pw;

        // PV: A-frag = 512 B contiguous wave load from vtf block kb = t*8+wv
        const _Float16* vb = vfb + ((size_t)(t*8 + wv) << 10) + (fr << 4) + (kg << 2);
        #pragma unroll
        for (int db = 0; db < 4; ++db) {
            h4_t va = *(const h4_t*)(vb + db*256);
            acc[db] = __builtin_amdgcn_mfma_f32_16x16x16f16(va, pw, acc[db], 0,0,0);
        }

        LGKM0();                   // PB writes landed
        BARRIER();                 // whole P tile ready

        // coalesced NON-TEMPORAL store: 16 rows x 512 B full lines, bypass L2
        h4_t pr = *(const h4_t*)&PB[cur][sq][sc << 2];
        f4raw o = { (float)pr[0], (float)pr[1], (float)pr[2], (float)pr[3] };
        __builtin_nontemporal_store(o, (f4raw*)(abase + (size_t)t * 128));

        cur ^= 1;
    }

    // ---- epilogue: 8-way k-slice reduce (aliases K buffer, exactly 32 KB) ----
    __syncthreads();
    {
        float* pt = (float*)KBuf;            // [8][16][64]
        #pragma unroll
        for (int db = 0; db < 4; ++db) {
            float4 o = { acc[db].x, acc[db].y, acc[db].z, acc[db].w };
            *(float4*)(pt + wv*1024 + fr*64 + db*16 + (kg << 2)) = o;
        }
    }
    __syncthreads();
    {
        float* pt = (float*)KBuf;
        const int e = tid << 1;              // 512 thr x 2 floats = 16x64
        const int q = e >> 6, d = e & 63;
        float2 r2 = {0.f, 0.f};
        #pragma unroll
        for (int w = 0; w < 8; ++w) {
            float2 t2 = *(float2*)(pt + w*1024 + q*64 + d);
            r2.x += t2.x; r2.y += t2.y;
        }
        *(float2*)(ctx + slab + (size_t)(q0 + q) * DHD + d) = r2;
    }
}

// ---------------------------------------------------------------------------
// Residual + LayerNorm: out = LN(resid + x) * gamma + beta, one row per block
// ---------------------------------------------------------------------------
__global__ __launch_bounds__(128) void ln_kernel(
    const float* __restrict__ resid, const float* __restrict__ x,
    const float* __restrict__ gamma, const float* __restrict__ beta,
    float* __restrict__ out)
{
    const int row = blockIdx.x;
    const int tid = threadIdx.x;
    const size_t base = (size_t)row * DMODEL + tid*4;

    float4 v = *(const float4*)(x + base);
    float4 rq = *(const float4*)(resid + base);
    v.x += rq.x; v.y += rq.y; v.z += rq.z; v.w += rq.w;

    float s  = v.x + v.y + v.z + v.w;
    float ss = v.x*v.x + v.y*v.y + v.z*v.z + v.w*v.w;
    #pragma unroll
    for (int d = 1; d < 64; d <<= 1) { s += __shfl_xor(s, d); ss += __shfl_xor(ss, d); }

    __shared__ float red[2][2];
    const int wv = tid >> 6;
    if ((tid & 63) == 0) { red[wv][0] = s; red[wv][1] = ss; }
    __syncthreads();
    s  = red[0][0] + red[1][0];
    ss = red[0][1] + red[1][1];

    const float mu  = s * (1.0f/512.0f);
    const float var = ss * (1.0f/512.0f) - mu*mu;
    const float rs  = rsqrtf(var + 1e-5f);

    float4 g = *(const float4*)(gamma + tid*4);
    float4 b = *(const float4*)(beta + tid*4);
    float4 o;
    o.x = (v.x - mu) * rs * g.x + b.x;
    o.y = (v.y - mu) * rs * g.y + b.y;
    o.z = (v.z - mu) * rs * g.z + b.z;
    o.w = (v.w - mu) * rs * g.w + b.w;
    *(float4*)(out + base) = o;
}

// ---------------------------------------------------------------------------
extern "C" void kernel_launch(void* const* d_in, const int* in_sizes, int n_in,
                              void* d_out, int out_size, void* d_ws, size_t ws_size,
                              hipStream_t stream)
{
    const float* query = (const float*)d_in[0];
    const float* key   = (const float*)d_in[1];
    const float* value = (const float*)d_in[2];
    const float* Wq = (const float*)d_in[3];
    const float* bq = (const float*)d_in[4];
    const float* Wk = (const float*)d_in[5];
    const float* bk = (const float*)d_in[6];
    const float* Wv = (const float*)d_in[7];
    const float* bv = (const float*)d_in[8];
    const float* Wo = (const float*)d_in[9];
    const float* bo = (const float*)d_in[10];
    const float* gamma = (const float*)d_in[11];
    const float* beta  = (const float*)d_in[12];

    float* out  = (float*)d_out;            // [B,L,D] = 4,194,304 f32
    float* attn = out + 4194304;            // [32,2048,2048] f32

    const size_t NTOK = (size_t)8192 * 512; // 4,194,304 elements
    short* qv = (short*)d_ws;               // f16 projected tensors
    short* kv = qv + NTOK;
    short* vf = kv + NTOK;
    short* vtf = vf + NTOK;                 // fragment-major V^T per head
    // obuf aliases qv/kv (dead after attn_kernel); ws requirement = 32 MB
    float* obuf = (float*)d_ws;

    dim3 pgrid(8, 128), pblk(256);
    proj_gemm<3><<<pgrid, pblk, 0, stream>>>(query, Wq, bq, nullptr, qv);
    proj_gemm<3><<<pgrid, pblk, 0, stream>>>(key,   Wk, bk, nullptr, kv);
    proj_gemm<3><<<pgrid, pblk, 0, stream>>>(value, Wv, bv, nullptr, vf);

    vtransf_kernel<<<dim3(32, 32), 256, 0, stream>>>(vf, vtf);

    attn_kernel<<<4096, 512, 0, stream>>>((const _Float16*)qv, (const _Float16*)kv,
                                          (const _Float16*)vtf, attn, out /*ctx*/);

    proj_gemm<0><<<pgrid, pblk, 0, stream>>>(out /*ctx*/, Wo, bo, obuf, nullptr);
    ln_kernel<<<8192, 128, 0, stream>>>(query, obuf, gamma, beta, out);
}

// Round 12
// 282.241 us; speedup vs baseline: 1.8251x; 1.0538x over previous
//
#include <hip/hip_runtime.h>

// Problem constants
#define LSEQ 2048
#define DMODEL 512
#define DHD 64          // head dim of the (faithful) raw view
#define SLAB (LSEQ*DHD) // 131072 elements per contiguous head slab

typedef __attribute__((ext_vector_type(8))) short short8;
typedef __attribute__((ext_vector_type(4))) float f32x4;
typedef float f4raw __attribute__((ext_vector_type(4)));   // raw clang vector (NT-store legal)
typedef _Float16 half8 __attribute__((ext_vector_type(8)));
typedef _Float16 h4_t  __attribute__((ext_vector_type(4)));

__device__ __forceinline__ short f2bf(float x) {   // round-to-nearest-even bf16
    union { float f; unsigned u; } v; v.f = x;
    unsigned r = v.u + 0x7FFF + ((v.u >> 16) & 1);
    return (short)(r >> 16);
}
__device__ __forceinline__ float bf2f(short h) {
    union { float f; unsigned u; } v; v.u = ((unsigned)(unsigned short)h) << 16;
    return v.f;
}

// direct global->LDS async copy, 16 B per lane (dest = wave-uniform base + lane*16)
#define GLOAD_LDS16(g, l) __builtin_amdgcn_global_load_lds( \
    (const __attribute__((address_space(1))) void*)(g),     \
    (__attribute__((address_space(3))) void*)(l), 16, 0, 0)

#define VMCNT0()  asm volatile("s_waitcnt vmcnt(0)" ::: "memory")
#define VMCNT2()  asm volatile("s_waitcnt vmcnt(2)" ::: "memory")
#define VMCNT4()  asm volatile("s_waitcnt vmcnt(4)" ::: "memory")
#define VMCNT6()  asm volatile("s_waitcnt vmcnt(6)" ::: "memory")
#define LGKM0()   asm volatile("s_waitcnt lgkmcnt(0)" ::: "memory")
#define BARRIER() do { __builtin_amdgcn_s_barrier(); __builtin_amdgcn_sched_barrier(0); } while (0)

// ---------------------------------------------------------------------------
// Projection GEMM: C[8192,512] = A[8192,512] @ W[512,512]^T + bias
// Internally split-f32 precision: a*w ~= ah*wh + ah*wl + al*wh (3 bf16 MFMAs).
// MODE 0: write f32 Cf.   MODE 3: write f16 C0 (round once at the end).
// ---------------------------------------------------------------------------
template<int MODE>
__global__ __launch_bounds__(256) void proj_gemm(
    const float* __restrict__ A, const float* __restrict__ W,
    const float* __restrict__ bias, float* __restrict__ Cf,
    short* __restrict__ C0)
{
    __shared__ __align__(16) short Ah[64][40], Al[64][40], Bh[64][40], Bl[64][40];

    const int tid  = threadIdx.x;
    const int lane = tid & 63, wv = tid >> 6;
    const int wm = wv >> 1, wn = wv & 1;
    const int fr = lane & 15, kg = lane >> 4;
    const int m0 = blockIdx.y * 64, n0 = blockIdx.x * 64;

    f32x4 acc[2][2];
    #pragma unroll
    for (int i = 0; i < 2; ++i)
        #pragma unroll
        for (int j = 0; j < 2; ++j) { f32x4 z = {0.f,0.f,0.f,0.f}; acc[i][j] = z; }

    const int srow = tid >> 2, sc8 = (tid & 3) << 3;

    for (int kt = 0; kt < 16; ++kt) {
        __syncthreads();
        {   // stage A/W tile, converting f32 -> hi/lo bf16
            const float* ap = A + (size_t)(m0 + srow) * DMODEL + kt*32 + sc8;
            float4 a0 = *(const float4*)ap;
            float4 a1 = *(const float4*)(ap + 4);
            float va[8] = {a0.x,a0.y,a0.z,a0.w,a1.x,a1.y,a1.z,a1.w};
            short8 h, l;
            #pragma unroll
            for (int j = 0; j < 8; ++j) { short hh = f2bf(va[j]); h[j] = hh; l[j] = f2bf(va[j] - bf2f(hh)); }
            *(short8*)&Ah[srow][sc8] = h; *(short8*)&Al[srow][sc8] = l;

            const float* wp = W + (size_t)(n0 + srow) * DMODEL + kt*32 + sc8;
            float4 b0 = *(const float4*)wp;
            float4 b1 = *(const float4*)(wp + 4);
            float vb[8] = {b0.x,b0.y,b0.z,b0.w,b1.x,b1.y,b1.z,b1.w};
            #pragma unroll
            for (int j = 0; j < 8; ++j) { short hh = f2bf(vb[j]); h[j] = hh; l[j] = f2bf(vb[j] - bf2f(hh)); }
            *(short8*)&Bh[srow][sc8] = h; *(short8*)&Bl[srow][sc8] = l;
        }
        __syncthreads();

        short8 ah[2], al[2], bh[2], bl[2];
        #pragma unroll
        for (int mf = 0; mf < 2; ++mf) {
            ah[mf] = *(short8*)&Ah[wm*32 + mf*16 + fr][kg*8];
            al[mf] = *(short8*)&Al[wm*32 + mf*16 + fr][kg*8];
        }
        #pragma unroll
        for (int nf = 0; nf < 2; ++nf) {
            bh[nf] = *(short8*)&Bh[wn*32 + nf*16 + fr][kg*8];
            bl[nf] = *(short8*)&Bl[wn*32 + nf*16 + fr][kg*8];
        }
        #pragma unroll
        for (int mf = 0; mf < 2; ++mf)
            #pragma unroll
            for (int nf = 0; nf < 2; ++nf) {
                acc[mf][nf] = __builtin_amdgcn_mfma_f32_16x16x32_bf16(ah[mf], bh[nf], acc[mf][nf], 0,0,0);
                acc[mf][nf] = __builtin_amdgcn_mfma_f32_16x16x32_bf16(ah[mf], bl[nf], acc[mf][nf], 0,0,0);
                acc[mf][nf] = __builtin_amdgcn_mfma_f32_16x16x32_bf16(al[mf], bh[nf], acc[mf][nf], 0,0,0);
            }
    }

    // epilogue: C/D layout col=lane&15, row=(lane>>4)*4+reg
    #pragma unroll
    for (int mf = 0; mf < 2; ++mf)
        #pragma unroll
        for (int nf = 0; nf < 2; ++nf) {
            const int col = n0 + wn*32 + nf*16 + fr;
            const float bv = bias[col];
            #pragma unroll
            for (int r = 0; r < 4; ++r) {
                const int row = m0 + wm*32 + mf*16 + kg*4 + r;
                const float o = acc[mf][nf][r] + bv;
                const size_t idx = (size_t)row * DMODEL + col;
                if (MODE == 0) Cf[idx] = o;
                else           ((_Float16*)C0)[idx] = (_Float16)o;
            }
        }
}

// ---------------------------------------------------------------------------
// V transpose -> FRAGMENT-MAJOR layout: vtf[head][kb][d][ks] with k = kb*16+ks.
// PV A-fragment for (tile, d-block) is then one fully-contiguous 512 B wave
// load (lane offset fr*16 + kg*4 within a 256-half block).
// ---------------------------------------------------------------------------
__global__ __launch_bounds__(256) void vtransf_kernel(
    const short* __restrict__ vh, short* __restrict__ vtf)
{
    __shared__ short T[64][72];
    const int tid = threadIdx.x;
    const int s  = blockIdx.y;          // head 0..31
    const int t0 = blockIdx.x * 64;     // l-tile (4 kb blocks)
    const size_t slab = (size_t)s * SLAB;

    {   // read 64 l-rows x 64 d (coalesced 32 B / thread)
        const int r = tid >> 2, c0 = (tid & 3) << 4;
        const short* src = vh + slab + (size_t)(t0 + r) * DHD + c0;
        short8 a = *(const short8*)src;
        short8 b = *(const short8*)(src + 8);
        *(short8*)&T[r][c0]     = a;
        *(short8*)&T[r][c0 + 8] = b;
    }
    __syncthreads();
    {   // write vtf[(kb*64 + d)*16 + ks] = T[kbl*16 + ks][d]  (32 B / thread)
        const int kbl = tid >> 6, d = tid & 63;
        short8 o0, o1;
        #pragma unroll
        for (int j = 0; j < 8; ++j) { o0[j] = T[kbl*16 + j][d]; o1[j] = T[kbl*16 + 8 + j][d]; }
        short* dst = vtf + slab + ((size_t)((t0 >> 4) + kbl) * 64 + d) * 16;
        *(short8*)dst       = o0;
        *(short8*)(dst + 8) = o1;
    }
}

// ---------------------------------------------------------------------------
// Attention, one WG (512 thr / 8 waves) per (bh, 16-row q-tile). Single pass.
// SWAPPED QK^T: mfma(K, Q) -> lane holds P[k=i*128+wv*16+kg*4+{0..3}][q=fr].
//   Phase 1 is BARRIER-FREE: wave wv stages LDS rows [16wv,16wv+16) and reads
//   exactly those rows -> K tile is wave-private. 4-slot rotation (64 KB),
//   3 tiles in flight, counted vmcnt(6) (T4); 8 independent wave-pipelines.
//   Softmax: scalar per-lane m/li, 2 shfl_xor + small LDS combine.
//   Phase 2: PV from own regs + fragment-major V (512 B coalesced wave loads);
//            attn stored NON-TEMPORAL via f16 PB tile (dbuf, LGKM0+barrier).
//   Epilogue: 8-way k-slice reduce via LDS (aliases K buffer).
// ---------------------------------------------------------------------------
__global__ __launch_bounds__(512, 4) void attn_kernel(
    const _Float16* __restrict__ qf, const _Float16* __restrict__ kf,
    const _Float16* __restrict__ vtf,
    float* __restrict__ attn, float* __restrict__ ctx)
{
    __shared__ __align__(16) char KBuf[65536];        // 4 x 16 KB K tile slots
    __shared__ __align__(16) _Float16 PB[2][16][136]; // 8,704 B P tile (store path)
    __shared__ float redA[8][16];
    __shared__ float mrow[16], lirow[16];

    const int tid  = threadIdx.x;
    const int lane = tid & 63, wv = tid >> 6;
    const int fr = lane & 15, kg = lane >> 4;

    // head-major remap: all 128 q-tiles of head bh land on XCD (bh&7)
    const int wg  = blockIdx.x;
    const int rem = wg & 1023;
    const int q0  = (rem >> 3) << 4;               // q-tile * 16
    const int bh  = ((wg >> 10) << 3) + (rem & 7); // 0..31
    const size_t slab = (size_t)bh * SLAB;

    // Q fragments (B-operand: lane fr holds row q0+fr), replicated across waves
    half8 qa[2];
    #pragma unroll
    for (int ks = 0; ks < 2; ++ks)
        qa[ks] = *(const half8*)(qf + slab + (size_t)(q0 + fr) * DHD + ks*32 + kg*8);

    const int srow = lane >> 3;          // staging: row within 8-row block
    const int scb  = (lane & 7) ^ srow;  // pre-swizzled global 16B col-block

    f32x4 s[16];   // logit quads: k = i*128 + wv*16 + kg*4 + r,  q = q0 + fr

    // ---- Phase 1: QK^T (swapped), barrier-free per-wave 4-slot pipeline ----
    #define STAGE_K(TI, CUR) { \
        _Pragma("unroll") \
        for (int j = 0; j < 2; ++j) { \
            const int b = wv*2 + j; \
            GLOAD_LDS16(kf + slab + (size_t)((TI)*128 + b*8 + srow)*DHD + scb*8, \
                        KBuf + (CUR)*16384 + b*1024); \
        } }

    STAGE_K(0, 0);
    STAGE_K(1, 1);
    STAGE_K(2, 2);

    const int klo = (wv << 4) + fr;          // tile-local K row (wave-private range)
    const int sw  = fr & 7;                  // klo & 7
    #pragma unroll
    for (int i = 0; i < 16; ++i) {
        if (i + 3 < 16) STAGE_K(i + 3, (i + 3) & 3);

        // wait for tile i only: allowed outstanding = 2*min(3, 15-i)
        if      (i <= 12) VMCNT6();
        else if (i == 13) VMCNT4();
        else if (i == 14) VMCNT2();
        else              VMCNT0();

        const char* rp = KBuf + (i & 3)*16384 + (klo << 7);
        half8 kb0 = *(const half8*)(rp + ((kg ^ sw) << 4));
        half8 kb1 = *(const half8*)(rp + (((4 + kg) ^ sw) << 4));

        f32x4 a = {0.f,0.f,0.f,0.f};
        a = __builtin_amdgcn_mfma_f32_16x16x32_f16(kb0, qa[0], a, 0,0,0);  // SWAPPED
        a = __builtin_amdgcn_mfma_f32_16x16x32_f16(kb1, qa[1], a, 0,0,0);
        s[i] = a;
    }
    #undef STAGE_K

    // ---- softmax: all 4 quad comps share q = fr -> scalar m / li ----
    float m;
    {
        f32x4 mx = s[0];
        #pragma unroll
        for (int i = 1; i < 16; ++i) {
            mx.x = fmaxf(mx.x, s[i].x); mx.y = fmaxf(mx.y, s[i].y);
            mx.z = fmaxf(mx.z, s[i].z); mx.w = fmaxf(mx.w, s[i].w);
        }
        m = fmaxf(fmaxf(mx.x, mx.y), fmaxf(mx.z, mx.w));
        m = fmaxf(m, __shfl_xor(m, 16));
        m = fmaxf(m, __shfl_xor(m, 32));
    }
    if (lane < 16) redA[wv][lane] = m;
    __syncthreads();
    if (tid < 16) {
        float mm = redA[0][tid];
        #pragma unroll
        for (int w = 1; w < 8; ++w) mm = fmaxf(mm, redA[w][tid]);
        mrow[tid] = mm;
    }
    __syncthreads();
    m = mrow[fr];

    const float C = 8.0f * 1.44269504089f;   // SCALE=8 folded into log2e
    float sum = 0.f;
    #pragma unroll
    for (int i = 0; i < 16; ++i) {
        f32x4 p;
        p.x = exp2f((s[i].x - m) * C);
        p.y = exp2f((s[i].y - m) * C);
        p.z = exp2f((s[i].z - m) * C);
        p.w = exp2f((s[i].w - m) * C);
        s[i] = p;
        sum += (p.x + p.y) + (p.z + p.w);
    }
    sum += __shfl_xor(sum, 16);
    sum += __shfl_xor(sum, 32);
    if (lane < 16) redA[wv][lane] = sum;
    __syncthreads();
    if (tid < 16) {
        float l = 0.f;
        #pragma unroll
        for (int w = 0; w < 8; ++w) l += redA[w][tid];
        lirow[tid] = 1.0f / l;
    }
    __syncthreads();
    const float li = lirow[fr];

    // ---- Phase 2: PV (reg P + fragment-major V) + coalesced NT attn store ----
    f32x4 acc[4];
    #pragma unroll
    for (int db = 0; db < 4; ++db) { f32x4 z = {0.f,0.f,0.f,0.f}; acc[db] = z; }

    const _Float16* vfb = vtf + slab;        // fragment-major V
    const int sq = tid >> 5, sc = tid & 31;  // store mapping: row q, 4-col chunk
    float* abase = attn + ((size_t)bh * LSEQ + q0 + sq) * LSEQ + (sc << 2);

    int cur = 0;
    #pragma unroll
    for (int t = 0; t < 16; ++t) {
        // normalized P quad (k = t*128 + wv*16 + kg*4 + r, q = fr)
        f32x4 p = s[t];
        p.x *= li; p.y *= li; p.z *= li; p.w *= li;
        h4_t pw = { (_Float16)p.x, (_Float16)p.y, (_Float16)p.z, (_Float16)p.w };

        // PB write for the store path (8 B contiguous per lane)
        *(h4_t*)&PB[cur][fr][(wv << 4) + (kg << 2)] = pw;

        // PV: A-frag = 512 B contiguous wave load from vtf block kb = t*8+wv
        const _Float16* vb = vfb + ((size_t)(t*8 + wv) << 10) + (fr << 4) + (kg << 2);
        #pragma unroll
        for (int db = 0; db < 4; ++db) {
            h4_t va = *(const h4_t*)(vb + db*256);
            acc[db] = __builtin_amdgcn_mfma_f32_16x16x16f16(va, pw, acc[db], 0,0,0);
        }

        LGKM0();                   // PB writes (and prior PB store-reads) drained
        BARRIER();                 // whole P tile ready

        // coalesced NON-TEMPORAL store: 16 rows x 512 B full lines, bypass L2
        h4_t pr = *(const h4_t*)&PB[cur][sq][sc << 2];
        f4raw o = { (float)pr[0], (float)pr[1], (float)pr[2], (float)pr[3] };
        __builtin_nontemporal_store(o, (f4raw*)(abase + (size_t)t * 128));

        cur ^= 1;
    }

    // ---- epilogue: 8-way k-slice reduce (aliases K buffer) ----
    __syncthreads();
    {
        float* pt = (float*)KBuf;            // [8][16][64]
        #pragma unroll
        for (int db = 0; db < 4; ++db) {
            float4 o = { acc[db].x, acc[db].y, acc[db].z, acc[db].w };
            *(float4*)(pt + wv*1024 + fr*64 + db*16 + (kg << 2)) = o;
        }
    }
    __syncthreads();
    {
        float* pt = (float*)KBuf;
        const int e = tid << 1;              // 512 thr x 2 floats = 16x64
        const int q = e >> 6, d = e & 63;
        float2 r2 = {0.f, 0.f};
        #pragma unroll
        for (int w = 0; w < 8; ++w) {
            float2 t2 = *(float2*)(pt + w*1024 + q*64 + d);
            r2.x += t2.x; r2.y += t2.y;
        }
        *(float2*)(ctx + slab + (size_t)(q0 + q) * DHD + d) = r2;
    }
}

// ---------------------------------------------------------------------------
// Residual + LayerNorm: out = LN(resid + x) * gamma + beta, one row per block
// ---------------------------------------------------------------------------
__global__ __launch_bounds__(128) void ln_kernel(
    const float* __restrict__ resid, const float* __restrict__ x,
    const float* __restrict__ gamma, const float* __restrict__ beta,
    float* __restrict__ out)
{
    const int row = blockIdx.x;
    const int tid = threadIdx.x;
    const size_t base = (size_t)row * DMODEL + tid*4;

    float4 v = *(const float4*)(x + base);
    float4 rq = *(const float4*)(resid + base);
    v.x += rq.x; v.y += rq.y; v.z += rq.z; v.w += rq.w;

    float s  = v.x + v.y + v.z + v.w;
    float ss = v.x*v.x + v.y*v.y + v.z*v.z + v.w*v.w;
    #pragma unroll
    for (int d = 1; d < 64; d <<= 1) { s += __shfl_xor(s, d); ss += __shfl_xor(ss, d); }

    __shared__ float red[2][2];
    const int wv = tid >> 6;
    if ((tid & 63) == 0) { red[wv][0] = s; red[wv][1] = ss; }
    __syncthreads();
    s  = red[0][0] + red[1][0];
    ss = red[0][1] + red[1][1];

    const float mu  = s * (1.0f/512.0f);
    const float var = ss * (1.0f/512.0f) - mu*mu;
    const float rs  = rsqrtf(var + 1e-5f);

    float4 g = *(const float4*)(gamma + tid*4);
    float4 b = *(const float4*)(beta + tid*4);
    float4 o;
    o.x = (v.x - mu) * rs * g.x + b.x;
    o.y = (v.y - mu) * rs * g.y + b.y;
    o.z = (v.z - mu) * rs * g.z + b.z;
    o.w = (v.w - mu) * rs * g.w + b.w;
    *(float4*)(out + base) = o;
}

// ---------------------------------------------------------------------------
extern "C" void kernel_launch(void* const* d_in, const int* in_sizes, int n_in,
                              void* d_out, int out_size, void* d_ws, size_t ws_size,
                              hipStream_t stream)
{
    const float* query = (const float*)d_in[0];
    const float* key   = (const float*)d_in[1];
    const float* value = (const float*)d_in[2];
    const float* Wq = (const float*)d_in[3];
    const float* bq = (const float*)d_in[4];
    const float* Wk = (const float*)d_in[5];
    const float* bk = (const float*)d_in[6];
    const float* Wv = (const float*)d_in[7];
    const float* bv = (const float*)d_in[8];
    const float* Wo = (const float*)d_in[9];
    const float* bo = (const float*)d_in[10];
    const float* gamma = (const float*)d_in[11];
    const float* beta  = (const float*)d_in[12];

    float* out  = (float*)d_out;            // [B,L,D] = 4,194,304 f32
    float* attn = out + 4194304;            // [32,2048,2048] f32

    const size_t NTOK = (size_t)8192 * 512; // 4,194,304 elements
    short* qv = (short*)d_ws;               // f16 projected tensors
    short* kv = qv + NTOK;
    short* vf = kv + NTOK;
    short* vtf = vf + NTOK;                 // fragment-major V^T per head
    // obuf aliases qv/kv (dead after attn_kernel); ws requirement = 32 MB
    float* obuf = (float*)d_ws;

    dim3 pgrid(8, 128), pblk(256);
    proj_gemm<3><<<pgrid, pblk, 0, stream>>>(query, Wq, bq, nullptr, qv);
    proj_gemm<3><<<pgrid, pblk, 0, stream>>>(key,   Wk, bk, nullptr, kv);
    proj_gemm<3><<<pgrid, pblk, 0, stream>>>(value, Wv, bv, nullptr, vf);

    vtransf_kernel<<<dim3(32, 32), 256, 0, stream>>>(vf, vtf);

    attn_kernel<<<4096, 512, 0, stream>>>((const _Float16*)qv, (const _Float16*)kv,
                                          (const _Float16*)vtf, attn, out /*ctx*/);

    proj_gemm<0><<<pgrid, pblk, 0, stream>>>(out /*ctx*/, Wo, bo, obuf, nullptr);
    ln_kernel<<<8192, 128, 0, stream>>>(query, obuf, gamma, beta, out);
}